// Round 4
// baseline (729.089 us; speedup 1.0000x reference)
//
#include <hip/hip_runtime.h>
#include <hip/hip_bf16.h>

// RGCN layer: out = x@W_self + b_self + sum_t [ mean_t(x[src]) @ W[t] + (deg_t>0)*b[t] ]
// v4: k_fused is LDS-free and barrier-free.
//   - A-fragments aggregated directly in registers: node = (wv,l16), its 4 lanes
//     (quad=0..3) each own k-chunks {ks*32+quad*8}, matching the MFMA A layout.
//   - B-fragments read straight from global wt (160 KB, L1/L2-resident broadcast).
//   - LDS 52 KB -> 0, occupancy 3 -> 5 blocks/CU (launch_bounds(256,5)), no barriers:
//     round-3 counters showed a latency-bound gather (VALU 26%, MFMA 6%, occ 30%).
// CSR build (v3): count+rank atomics, block-scan offsets, atomic-free scatter,
// x pre-converted to bf16 (xb) to halve gather bytes.

namespace {

constexpr int N  = 200000;  // nodes
constexpr int T  = 4;       // etypes
constexpr int E  = 500000;  // edges per etype
constexpr int D  = 128;     // d_in == d_out
constexpr int NT = 64;      // nodes per block tile

constexpr int CNT_B = (T * E + 255) / 256;          // 7813
constexpr int PX_B  = (N * D / 8) / 256;            // 12500 (exact)
constexpr int PW_B  = (5 * D * D / 8 + 255) / 256;  // 40

typedef __bf16 bf16x8 __attribute__((ext_vector_type(8)));
typedef float  f32x4  __attribute__((ext_vector_type(4)));

__global__ void k_zero(int* __restrict__ p, int n) {
  int i = blockIdx.x * 256 + threadIdx.x;
  if (i < n) p[i] = 0;
}

// Fused: edge count (+rank) | x fp32->bf16 | W^T pack to bf16.
template <bool XB>
__global__ void k_prep(const int* __restrict__ dst, int* __restrict__ cnt,
                       int* __restrict__ rank, const float* __restrict__ x,
                       __bf16* __restrict__ xb, const float* __restrict__ W,
                       const float* __restrict__ Wself, __bf16* __restrict__ wt) {
  const int bid = blockIdx.x;
  const int tid = threadIdx.x;
  if (bid < CNT_B) {
    int i = bid * 256 + tid;
    if (i < T * E) {
      int t = i / E;
      rank[i] = atomicAdd(&cnt[t * N + dst[i]], 1);
    }
  } else if (XB && bid < CNT_B + PX_B) {
    int i = (bid - CNT_B) * 256 + tid;  // one per 8 floats
    if (i < N * D / 8) {
      const float4* xs = (const float4*)(x + i * 8);
      float4 a = xs[0], c = xs[1];
      bf16x8 v;
      v[0] = (__bf16)a.x; v[1] = (__bf16)a.y; v[2] = (__bf16)a.z; v[3] = (__bf16)a.w;
      v[4] = (__bf16)c.x; v[5] = (__bf16)c.y; v[6] = (__bf16)c.z; v[7] = (__bf16)c.w;
      *(bf16x8*)(xb + i * 8) = v;
    }
  } else {
    int i = (bid - CNT_B - (XB ? PX_B : 0)) * 256 + tid;  // one per 8 wt elems
    if (i < 5 * D * D / 8) {
      int base = i * 8;
      int p = base >> 14, rem = base & 16383;
      int n = rem >> 7, k0 = rem & 127;
      const float* Wsrc = (p < 4) ? (W + (size_t)p * D * D) : Wself;  // [k][n]
      bf16x8 v;
#pragma unroll
      for (int j = 0; j < 8; ++j) v[j] = (__bf16)Wsrc[(k0 + j) * D + n];
      *(bf16x8*)(wt + base) = v;
    }
  }
}

// Exclusive offsets via block scan + one global-cursor atomic per block.
__global__ void k_offsets(const int* __restrict__ cnt, int* __restrict__ offs,
                          int* __restrict__ cursor) {
  __shared__ int s[256];
  __shared__ int base;
  int tid = threadIdx.x;
  int i = blockIdx.x * 256 + tid;
  int c = (i < T * N) ? cnt[i] : 0;
  s[tid] = c;
  __syncthreads();
  for (int d = 1; d < 256; d <<= 1) {
    int v = (tid >= d) ? s[tid - d] : 0;
    __syncthreads();
    s[tid] += v;
    __syncthreads();
  }
  if (tid == 255) base = atomicAdd(cursor, s[255]);
  __syncthreads();
  if (i < T * N) offs[i] = base + s[tid] - c;  // exclusive
}

// No atomics: pos = offs[bucket] + rank (rank recorded during count).
__global__ void k_scatter(const int* __restrict__ src, const int* __restrict__ dst,
                          const int* __restrict__ offs, const int* __restrict__ rank,
                          int* __restrict__ eid) {
  int i = blockIdx.x * 256 + threadIdx.x;
  if (i >= T * E) return;
  int t = i / E;
  int pos = offs[t * N + dst[i]] + rank[i];
  eid[pos] = src[i];
}

// Fused aggregate + bf16 MFMA GEMM. 256 threads (4 waves), 64-node tile.
// Zero LDS, zero barriers. Node = nb + 16*wv + l16; its 4 lanes (quad) own
// k-chunks ks*32+quad*8 (== MFMA A-fragment layout, so no staging transform).
template <bool XB>
__global__ __launch_bounds__(256, 5) void k_fused(
    const float* __restrict__ x, const __bf16* __restrict__ xb,
    const __bf16* __restrict__ wt, const float* __restrict__ b,
    const float* __restrict__ bself, const int* __restrict__ cnt,
    const int* __restrict__ offs, const int* __restrict__ eid,
    float* __restrict__ out) {
  const int tid  = threadIdx.x;
  const int nb   = blockIdx.x * NT;
  const int wv   = tid >> 6;   // wave 0..3 -> node rows 16*wv..16*wv+15
  const int lane = tid & 63;
  const int quad = lane >> 4;  // 0..3: owns k = {ks*32 + quad*8 + j}
  const int l16  = lane & 15;
  const int node = nb + 16 * wv + l16;

  f32x4 acc[8];
#pragma unroll
  for (int ct = 0; ct < 8; ++ct) acc[ct] = (f32x4){0.f, 0.f, 0.f, 0.f};

  for (int pass = 0; pass < 5; ++pass) {
    const bool self = (pass == 4);

    // ---- A-fragment: mean-aggregate straight into registers
    bf16x8 af[4];
    if (self) {
      if (XB) {
#pragma unroll
        for (int ks = 0; ks < 4; ++ks)
          af[ks] = *(const bf16x8*)(xb + (size_t)node * D + ks * 32 + quad * 8);
      } else {
#pragma unroll
        for (int ks = 0; ks < 4; ++ks) {
          const float* xr = x + (size_t)node * D + ks * 32 + quad * 8;
          float4 a = *(const float4*)xr;
          float4 c = *(const float4*)(xr + 4);
          bf16x8 v;
          v[0] = (__bf16)a.x; v[1] = (__bf16)a.y; v[2] = (__bf16)a.z; v[3] = (__bf16)a.w;
          v[4] = (__bf16)c.x; v[5] = (__bf16)c.y; v[6] = (__bf16)c.z; v[7] = (__bf16)c.w;
          af[ks] = v;
        }
      }
    } else {
      float r[4][8];
#pragma unroll
      for (int ks = 0; ks < 4; ++ks)
#pragma unroll
        for (int j = 0; j < 8; ++j) r[ks][j] = 0.f;

      const int bucket = pass * N + node;
      const int base = offs[bucket];
      const int deg  = cnt[bucket];
      int nxt = (deg > 0) ? eid[base] : 0;
      for (int e = 0; e < deg; ++e) {
        const int sidx = nxt;
        nxt = eid[base + e + 1];  // prefetch; slack word follows eid (harmless)
        if (XB) {
#pragma unroll
          for (int ks = 0; ks < 4; ++ks) {
            bf16x8 v = *(const bf16x8*)(xb + (size_t)sidx * D + ks * 32 + quad * 8);
#pragma unroll
            for (int j = 0; j < 8; ++j) r[ks][j] += (float)v[j];
          }
        } else {
#pragma unroll
          for (int ks = 0; ks < 4; ++ks) {
            const float* xr = x + (size_t)sidx * D + ks * 32 + quad * 8;
            float4 a = *(const float4*)xr;
            float4 c = *(const float4*)(xr + 4);
            r[ks][0] += a.x; r[ks][1] += a.y; r[ks][2] += a.z; r[ks][3] += a.w;
            r[ks][4] += c.x; r[ks][5] += c.y; r[ks][6] += c.z; r[ks][7] += c.w;
          }
        }
      }
      const float inv = (deg > 0) ? (1.0f / (float)deg) : 0.0f;
#pragma unroll
      for (int ks = 0; ks < 4; ++ks) {
        bf16x8 v;
#pragma unroll
        for (int j = 0; j < 8; ++j) v[j] = (__bf16)(r[ks][j] * inv);
        af[ks] = v;
      }
    }

    // ---- MFMA: acc[16 x 128 per wave] += A @ B, B straight from global wt.
    // B-frag: B[k=quad*8+j][n=16*ct+l16] from wt[n][k] (L1/L2-resident).
    const __bf16* wp = wt + pass * D * D;
#pragma unroll
    for (int ks = 0; ks < 4; ++ks) {
#pragma unroll
      for (int ct = 0; ct < 8; ++ct) {
        bf16x8 bfr = *(const bf16x8*)(wp + (16 * ct + l16) * D + ks * 32 + quad * 8);
        acc[ct] = __builtin_amdgcn_mfma_f32_16x16x32_bf16(af[ks], bfr, acc[ct], 0, 0, 0);
      }
    }

    // ---- bias: b[t] gated on deg>0 per output row; b_self unconditional.
    // C/D layout: col = 16*ct + l16, row = 16*wv + quad*4 + reg.
    {
      const float* bt = self ? bself : (b + pass * D);
      bool rowon[4];
#pragma unroll
      for (int r = 0; r < 4; ++r) {
        rowon[r] = self ? true : (cnt[pass * N + nb + 16 * wv + quad * 4 + r] > 0);
      }
#pragma unroll
      for (int ct = 0; ct < 8; ++ct) {
        float bv = bt[16 * ct + l16];
#pragma unroll
        for (int r = 0; r < 4; ++r)
          if (rowon[r]) acc[ct][r] += bv;
      }
    }
  }

  // ---- epilogue: each store instr covers 4 full 64B lines (4 rows x 16 lanes)
#pragma unroll
  for (int ct = 0; ct < 8; ++ct) {
#pragma unroll
    for (int r = 0; r < 4; ++r) {
      out[(nb + 16 * wv + quad * 4 + r) * D + 16 * ct + l16] = acc[ct][r];
    }
  }
}

}  // namespace

extern "C" void kernel_launch(void* const* d_in, const int* in_sizes, int n_in,
                              void* d_out, int out_size, void* d_ws, size_t ws_size,
                              hipStream_t stream) {
  const float* x     = (const float*)d_in[0];
  const float* W     = (const float*)d_in[1];
  const float* b     = (const float*)d_in[2];
  const float* Wself = (const float*)d_in[3];
  const float* bself = (const float*)d_in[4];
  const int*   src   = (const int*)d_in[5];
  const int*   dst   = (const int*)d_in[6];
  float* out = (float*)d_out;

  // ws (ints): cnt[T*N] | cursor(+pad)[4] | offs[T*N] | eid[T*E] | rank[T*E]
  //            then bf16: wt[5*D*D] | xb[N*D]
  int* cnt    = (int*)d_ws;
  int* cursor = cnt + T * N;
  int* offs   = cursor + 4;
  int* eid    = offs + T * N;
  int* rank   = eid + T * E;   // rank doubles as slack for eid's +1 prefetch
  __bf16* wt  = (__bf16*)(rank + T * E);
  __bf16* xb  = wt + 5 * D * D;

  const size_t need_xb =
      (size_t)(T * N + 4 + T * N + T * E + T * E) * 4 + (size_t)5 * D * D * 2 +
      (size_t)N * D * 2;
  const bool use_xb = ws_size >= need_xb;

  k_zero<<<(T * N + 4 + 255) / 256, 256, 0, stream>>>(cnt, T * N + 4);
  if (use_xb) {
    k_prep<true><<<CNT_B + PX_B + PW_B, 256, 0, stream>>>(dst, cnt, rank, x, xb,
                                                          W, Wself, wt);
  } else {
    k_prep<false><<<CNT_B + PW_B, 256, 0, stream>>>(dst, cnt, rank, x, xb, W,
                                                    Wself, wt);
  }
  k_offsets<<<(T * N + 255) / 256, 256, 0, stream>>>(cnt, offs, cursor);
  k_scatter<<<(T * E + 255) / 256, 256, 0, stream>>>(src, dst, offs, rank, eid);
  if (use_xb) {
    k_fused<true><<<N / NT, 256, 0, stream>>>(x, xb, wt, b, bself, cnt, offs,
                                              eid, out);
  } else {
    k_fused<false><<<N / NT, 256, 0, stream>>>(x, xb, wt, b, bself, cnt, offs,
                                               eid, out);
  }
}

// Round 5
// 679.996 us; speedup vs baseline: 1.0722x; 1.0722x over previous
//
#include <hip/hip_runtime.h>
#include <hip/hip_bf16.h>

// RGCN layer: out = x@W_self + b_self + sum_t [ mean_t(x[src]) @ W[t] + (deg_t>0)*b[t] ]
// v5: v4's LDS-free k_fused, with MLP restored.
//   Round-4 regression root cause: launch_bounds(256,5) -> 48-VGPR cap killed the
//   gather loop's software pipeline (1 edge's loads in flight). VALU/MFMA absolute
//   work was unchanged; only memory idle grew. Fix: launch_bounds(256,4) (128-VGPR
//   cap) + explicit 2-edge pipelined gather (8 x 16B loads in flight, ids
//   prefetched 2 ahead).
// CSR build (v3): count+rank atomics, block-scan offsets, atomic-free scatter,
// x pre-converted to bf16 (xb) to halve gather bytes.

namespace {

constexpr int N  = 200000;  // nodes
constexpr int T  = 4;       // etypes
constexpr int E  = 500000;  // edges per etype
constexpr int D  = 128;     // d_in == d_out
constexpr int NT = 64;      // nodes per block tile

constexpr int CNT_B = (T * E + 255) / 256;          // 7813
constexpr int PX_B  = (N * D / 8) / 256;            // 12500 (exact)
constexpr int PW_B  = (5 * D * D / 8 + 255) / 256;  // 40

typedef __bf16 bf16x8 __attribute__((ext_vector_type(8)));
typedef float  f32x4  __attribute__((ext_vector_type(4)));

__global__ void k_zero(int* __restrict__ p, int n) {
  int i = blockIdx.x * 256 + threadIdx.x;
  if (i < n) p[i] = 0;
}

// Fused: edge count (+rank) | x fp32->bf16 | W^T pack to bf16.
template <bool XB>
__global__ void k_prep(const int* __restrict__ dst, int* __restrict__ cnt,
                       int* __restrict__ rank, const float* __restrict__ x,
                       __bf16* __restrict__ xb, const float* __restrict__ W,
                       const float* __restrict__ Wself, __bf16* __restrict__ wt) {
  const int bid = blockIdx.x;
  const int tid = threadIdx.x;
  if (bid < CNT_B) {
    int i = bid * 256 + tid;
    if (i < T * E) {
      int t = i / E;
      rank[i] = atomicAdd(&cnt[t * N + dst[i]], 1);
    }
  } else if (XB && bid < CNT_B + PX_B) {
    int i = (bid - CNT_B) * 256 + tid;  // one per 8 floats
    if (i < N * D / 8) {
      const float4* xs = (const float4*)(x + i * 8);
      float4 a = xs[0], c = xs[1];
      bf16x8 v;
      v[0] = (__bf16)a.x; v[1] = (__bf16)a.y; v[2] = (__bf16)a.z; v[3] = (__bf16)a.w;
      v[4] = (__bf16)c.x; v[5] = (__bf16)c.y; v[6] = (__bf16)c.z; v[7] = (__bf16)c.w;
      *(bf16x8*)(xb + i * 8) = v;
    }
  } else {
    int i = (bid - CNT_B - (XB ? PX_B : 0)) * 256 + tid;  // one per 8 wt elems
    if (i < 5 * D * D / 8) {
      int base = i * 8;
      int p = base >> 14, rem = base & 16383;
      int n = rem >> 7, k0 = rem & 127;
      const float* Wsrc = (p < 4) ? (W + (size_t)p * D * D) : Wself;  // [k][n]
      bf16x8 v;
#pragma unroll
      for (int j = 0; j < 8; ++j) v[j] = (__bf16)Wsrc[(k0 + j) * D + n];
      *(bf16x8*)(wt + base) = v;
    }
  }
}

// Exclusive offsets via block scan + one global-cursor atomic per block.
__global__ void k_offsets(const int* __restrict__ cnt, int* __restrict__ offs,
                          int* __restrict__ cursor) {
  __shared__ int s[256];
  __shared__ int base;
  int tid = threadIdx.x;
  int i = blockIdx.x * 256 + tid;
  int c = (i < T * N) ? cnt[i] : 0;
  s[tid] = c;
  __syncthreads();
  for (int d = 1; d < 256; d <<= 1) {
    int v = (tid >= d) ? s[tid - d] : 0;
    __syncthreads();
    s[tid] += v;
    __syncthreads();
  }
  if (tid == 255) base = atomicAdd(cursor, s[255]);
  __syncthreads();
  if (i < T * N) offs[i] = base + s[tid] - c;  // exclusive
}

// No atomics: pos = offs[bucket] + rank (rank recorded during count).
__global__ void k_scatter(const int* __restrict__ src, const int* __restrict__ dst,
                          const int* __restrict__ offs, const int* __restrict__ rank,
                          int* __restrict__ eid) {
  int i = blockIdx.x * 256 + threadIdx.x;
  if (i >= T * E) return;
  int t = i / E;
  int pos = offs[t * N + dst[i]] + rank[i];
  eid[pos] = src[i];
}

// Fused aggregate + bf16 MFMA GEMM. 256 threads (4 waves), 64-node tile.
// Zero LDS, zero barriers. Node = nb + 16*wv + l16; its 4 lanes (quad) own
// k-chunks ks*32+quad*8 (== MFMA A-fragment layout, so no staging transform).
// launch_bounds(256,4): 128-VGPR cap -- enough for the 2-edge pipelined gather.
template <bool XB>
__global__ __launch_bounds__(256, 4) void k_fused(
    const float* __restrict__ x, const __bf16* __restrict__ xb,
    const __bf16* __restrict__ wt, const float* __restrict__ b,
    const float* __restrict__ bself, const int* __restrict__ cnt,
    const int* __restrict__ offs, const int* __restrict__ eid,
    float* __restrict__ out) {
  const int tid  = threadIdx.x;
  const int nb   = blockIdx.x * NT;
  const int wv   = tid >> 6;   // wave 0..3 -> node rows 16*wv..16*wv+15
  const int lane = tid & 63;
  const int quad = lane >> 4;  // 0..3: owns k = {ks*32 + quad*8 + j}
  const int l16  = lane & 15;
  const int node = nb + 16 * wv + l16;

  f32x4 acc[8];
#pragma unroll
  for (int ct = 0; ct < 8; ++ct) acc[ct] = (f32x4){0.f, 0.f, 0.f, 0.f};

  for (int pass = 0; pass < 5; ++pass) {
    const bool self = (pass == 4);

    // ---- A-fragment: mean-aggregate straight into registers
    bf16x8 af[4];
    if (self) {
      if (XB) {
#pragma unroll
        for (int ks = 0; ks < 4; ++ks)
          af[ks] = *(const bf16x8*)(xb + (size_t)node * D + ks * 32 + quad * 8);
      } else {
#pragma unroll
        for (int ks = 0; ks < 4; ++ks) {
          const float* xr = x + (size_t)node * D + ks * 32 + quad * 8;
          float4 a = *(const float4*)xr;
          float4 c = *(const float4*)(xr + 4);
          bf16x8 v;
          v[0] = (__bf16)a.x; v[1] = (__bf16)a.y; v[2] = (__bf16)a.z; v[3] = (__bf16)a.w;
          v[4] = (__bf16)c.x; v[5] = (__bf16)c.y; v[6] = (__bf16)c.z; v[7] = (__bf16)c.w;
          af[ks] = v;
        }
      }
    } else {
      float r[4][8];
#pragma unroll
      for (int ks = 0; ks < 4; ++ks)
#pragma unroll
        for (int j = 0; j < 8; ++j) r[ks][j] = 0.f;

      const int bucket = pass * N + node;
      const int base = offs[bucket];
      const int deg  = cnt[bucket];

      // 2-edge software pipeline: 8 x 16B loads in flight, ids prefetched
      // 2 ahead. eid over-reads up to eid[base+deg+1] land in rank[] slack.
      int id0 = (deg > 0) ? eid[base] : 0;
      int id1 = (deg > 1) ? eid[base + 1] : 0;
      int e = 0;
      if (XB) {
        for (; e + 2 <= deg; ) {
          const __bf16* r0 = xb + (size_t)id0 * D + quad * 8;
          const __bf16* r1 = xb + (size_t)id1 * D + quad * 8;
          bf16x8 va0 = *(const bf16x8*)(r0);
          bf16x8 va1 = *(const bf16x8*)(r0 + 32);
          bf16x8 va2 = *(const bf16x8*)(r0 + 64);
          bf16x8 va3 = *(const bf16x8*)(r0 + 96);
          bf16x8 vb0 = *(const bf16x8*)(r1);
          bf16x8 vb1 = *(const bf16x8*)(r1 + 32);
          bf16x8 vb2 = *(const bf16x8*)(r1 + 64);
          bf16x8 vb3 = *(const bf16x8*)(r1 + 96);
          e += 2;
          id0 = eid[base + e];
          id1 = eid[base + e + 1];
#pragma unroll
          for (int j = 0; j < 8; ++j) {
            r[0][j] += (float)va0[j]; r[1][j] += (float)va1[j];
            r[2][j] += (float)va2[j]; r[3][j] += (float)va3[j];
          }
#pragma unroll
          for (int j = 0; j < 8; ++j) {
            r[0][j] += (float)vb0[j]; r[1][j] += (float)vb1[j];
            r[2][j] += (float)vb2[j]; r[3][j] += (float)vb3[j];
          }
        }
        if (e < deg) {  // odd tail
          const __bf16* r0 = xb + (size_t)id0 * D + quad * 8;
#pragma unroll
          for (int ks = 0; ks < 4; ++ks) {
            bf16x8 v = *(const bf16x8*)(r0 + ks * 32);
#pragma unroll
            for (int j = 0; j < 8; ++j) r[ks][j] += (float)v[j];
          }
        }
      } else {
        for (; e < deg; ++e) {
          const int sidx = (e == 0) ? id0 : eid[base + e];
#pragma unroll
          for (int ks = 0; ks < 4; ++ks) {
            const float* xr = x + (size_t)sidx * D + ks * 32 + quad * 8;
            float4 a = *(const float4*)xr;
            float4 c = *(const float4*)(xr + 4);
            r[ks][0] += a.x; r[ks][1] += a.y; r[ks][2] += a.z; r[ks][3] += a.w;
            r[ks][4] += c.x; r[ks][5] += c.y; r[ks][6] += c.z; r[ks][7] += c.w;
          }
        }
      }
      const float inv = (deg > 0) ? (1.0f / (float)deg) : 0.0f;
#pragma unroll
      for (int ks = 0; ks < 4; ++ks) {
        bf16x8 v;
#pragma unroll
        for (int j = 0; j < 8; ++j) v[j] = (__bf16)(r[ks][j] * inv);
        af[ks] = v;
      }
    }

    // ---- MFMA: acc[16 x 128 per wave] += A @ B, B straight from global wt.
    // B-frag: B[k=quad*8+j][n=16*ct+l16] from wt[n][k] (L1/L2-resident).
    const __bf16* wp = wt + pass * D * D;
#pragma unroll
    for (int ks = 0; ks < 4; ++ks) {
#pragma unroll
      for (int ct = 0; ct < 8; ++ct) {
        bf16x8 bfr = *(const bf16x8*)(wp + (16 * ct + l16) * D + ks * 32 + quad * 8);
        acc[ct] = __builtin_amdgcn_mfma_f32_16x16x32_bf16(af[ks], bfr, acc[ct], 0, 0, 0);
      }
    }

    // ---- bias: b[t] gated on deg>0 per output row; b_self unconditional.
    // C/D layout: col = 16*ct + l16, row = 16*wv + quad*4 + reg.
    {
      const float* bt = self ? bself : (b + pass * D);
      bool rowon[4];
#pragma unroll
      for (int r = 0; r < 4; ++r) {
        rowon[r] = self ? true : (cnt[pass * N + nb + 16 * wv + quad * 4 + r] > 0);
      }
#pragma unroll
      for (int ct = 0; ct < 8; ++ct) {
        float bv = bt[16 * ct + l16];
#pragma unroll
        for (int r = 0; r < 4; ++r)
          if (rowon[r]) acc[ct][r] += bv;
      }
    }
  }

  // ---- epilogue: each store instr covers 4 full 64B lines (4 rows x 16 lanes)
#pragma unroll
  for (int ct = 0; ct < 8; ++ct) {
#pragma unroll
    for (int r = 0; r < 4; ++r) {
      out[(nb + 16 * wv + quad * 4 + r) * D + 16 * ct + l16] = acc[ct][r];
    }
  }
}

}  // namespace

extern "C" void kernel_launch(void* const* d_in, const int* in_sizes, int n_in,
                              void* d_out, int out_size, void* d_ws, size_t ws_size,
                              hipStream_t stream) {
  const float* x     = (const float*)d_in[0];
  const float* W     = (const float*)d_in[1];
  const float* b     = (const float*)d_in[2];
  const float* Wself = (const float*)d_in[3];
  const float* bself = (const float*)d_in[4];
  const int*   src   = (const int*)d_in[5];
  const int*   dst   = (const int*)d_in[6];
  float* out = (float*)d_out;

  // ws (ints): cnt[T*N] | cursor(+pad)[4] | offs[T*N] | eid[T*E] | rank[T*E]
  //            then bf16: wt[5*D*D] | xb[N*D]
  int* cnt    = (int*)d_ws;
  int* cursor = cnt + T * N;
  int* offs   = cursor + 4;
  int* eid    = offs + T * N;
  int* rank   = eid + T * E;   // rank doubles as slack for eid's +2 prefetch
  __bf16* wt  = (__bf16*)(rank + T * E);
  __bf16* xb  = wt + 5 * D * D;

  const size_t need_xb =
      (size_t)(T * N + 4 + T * N + T * E + T * E) * 4 + (size_t)5 * D * D * 2 +
      (size_t)N * D * 2;
  const bool use_xb = ws_size >= need_xb;

  k_zero<<<(T * N + 4 + 255) / 256, 256, 0, stream>>>(cnt, T * N + 4);
  if (use_xb) {
    k_prep<true><<<CNT_B + PX_B + PW_B, 256, 0, stream>>>(dst, cnt, rank, x, xb,
                                                          W, Wself, wt);
  } else {
    k_prep<false><<<CNT_B + PW_B, 256, 0, stream>>>(dst, cnt, rank, x, xb, W,
                                                    Wself, wt);
  }
  k_offsets<<<(T * N + 255) / 256, 256, 0, stream>>>(cnt, offs, cursor);
  k_scatter<<<(T * E + 255) / 256, 256, 0, stream>>>(src, dst, offs, rank, eid);
  if (use_xb) {
    k_fused<true><<<N / NT, 256, 0, stream>>>(x, xb, wt, b, bself, cnt, offs,
                                              eid, out);
  } else {
    k_fused<false><<<N / NT, 256, 0, stream>>>(x, xb, wt, b, bself, cnt, offs,
                                               eid, out);
  }
}